// Round 19
// baseline (39265.604 us; speedup 1.0000x reference)
//
#include <hip/hip_runtime.h>

typedef unsigned int u32;
typedef unsigned long long u64;

#define T    128
#define D    1024
#define HH   2048
#define NWG  256          // compute WGs; grid = NWG+1 (last = detector)
#define NTH  256

// ws layout:
//   int  go[64 lines]      @ byte 0      (64 lines x 256B = 16384)
//   float scores[128]      @ byte 16384
//   u64  Y[2][256][8]      @ byte 24576  (u64 idx 3072, 32768B)
//   u64  HODE[256][8]      @ byte 57344  (u64 idx 7168, 16384B)
//   u64  HNEW[256][8]      @ byte 73728  (u64 idx 9216, 16384B)
// memset 90112 B per launch (tags must reset between graph replays)
#define SC_OFFF   4096
#define Y_OFFU    3072
#define HODE_OFFU 7168
#define HNEW_OFFU 9216

constexpr float DP_A[5][5] = {
  {1.f/5.f, 0.f, 0.f, 0.f, 0.f},
  {3.f/40.f, 9.f/40.f, 0.f, 0.f, 0.f},
  {44.f/45.f, -56.f/15.f, 32.f/9.f, 0.f, 0.f},
  {19372.f/6561.f, -25360.f/2187.f, 64448.f/6561.f, -212.f/729.f, 0.f},
  {9017.f/3168.f, -355.f/33.f, 46732.f/5247.f, 49.f/176.f, -5103.f/18656.f}};
#define B0 (35.f/384.f)
#define B2 (500.f/1113.f)
#define B3 (125.f/192.f)
#define B4 (-2187.f/6784.f)
#define B5 (11.f/84.f)

__device__ inline void ld4(const float* p, float* f){
  float4 q = *reinterpret_cast<const float4*>(p);
  f[0]=q.x; f[1]=q.y; f[2]=q.z; f[3]=q.w;
}
__device__ inline void ld8(const float* p, float* f){
  float4 q0 = *reinterpret_cast<const float4*>(p);
  float4 q1 = *reinterpret_cast<const float4*>(p+4);
  f[0]=q0.x; f[1]=q0.y; f[2]=q0.z; f[3]=q0.w;
  f[4]=q1.x; f[5]=q1.y; f[6]=q1.z; f[7]=q1.w;
}
__device__ inline float dot8r(const float* w, const float* v){
  float s = w[0]*v[0];
  s += w[1]*v[1]; s += w[2]*v[2]; s += w[3]*v[3];
  s += w[4]*v[4]; s += w[5]*v[5]; s += w[6]*v[6]; s += w[7]*v[7];
  return s;
}
__device__ inline float cld(const float* p){
  return __hip_atomic_load(p, __ATOMIC_RELAXED, __HIP_MEMORY_SCOPE_AGENT);
}
__device__ inline void st64(u64* p, u64 v){
  __hip_atomic_store(p, v, __ATOMIC_RELAXED, __HIP_MEMORY_SCOPE_AGENT);
}
__device__ inline u64 ld64(const u64* p){
  return __hip_atomic_load(p, __ATOMIC_RELAXED, __HIP_MEMORY_SCOPE_AGENT);
}
__device__ inline u64 pack(float v, int ep){
  return ((u64)(u32)ep << 32) | (u64)__float_as_uint(v);
}

template<int NR>
__device__ inline void wave_reduce(float* p){
#pragma unroll
  for (int r=0;r<NR;++r){
    float v=p[r];
#pragma unroll
    for (int m=1;m<64;m<<=1) v += __shfl_xor(v, m, 64);
    p[r]=v;
  }
}

// consumer: bounded speculative tag-checked read; fallback = go-line wait.
__device__ inline void consume8(const u64* line, int ep, float* out, int* go,
                                int& dead, int tid, int g){
  if (dead) return;                      // WG-uniform
  u64 v[8]; int ok=0;
#pragma unroll
  for (int a=0;a<3;++a){
    ok = 1;
#pragma unroll
    for (int j=0;j<8;++j){ v[j]=ld64(line+j); ok &= ((int)(v[j]>>32) >= ep); }
    if (ok) break;
    __builtin_amdgcn_s_sleep(2);         // literal constant required
  }
  int nok = __syncthreads_count(ok);
  if (nok < NTH){                        // slow path: detector's go signal
    int bad=0;
    if (tid==0){
      int guard=0;
      while (__hip_atomic_load(go + 64*(g&63), __ATOMIC_RELAXED,
                               __HIP_MEMORY_SCOPE_AGENT) < ep){
        __builtin_amdgcn_s_sleep(2);
        if (++guard > (1<<18)) { bad=1; break; }
      }
    }
    if (__syncthreads_count(bad)) dead=1;
    if (!ok && !dead){
#pragma unroll
      for (int j=0;j<8;++j) v[j]=ld64(line+j);
    }
  }
#pragma unroll
  for (int j=0;j<8;++j) out[j]=__uint_as_float((u32)v[j]);
}

// detector-WG helpers: poll 256 lines (1 lane each), publish 64 go-lines
__device__ inline void det_wait(const u64* base, int ep, int tid, int& dead){
  if (dead) return;
  const u64* line = base + (size_t)tid*8;
  int bad=0, guard=0;
  for (;;){
    int ok=1;
#pragma unroll
    for (int j=0;j<8;++j) ok &= ((int)(ld64(line+j)>>32) >= ep);
    if (ok) break;
    __builtin_amdgcn_s_sleep(1);
    if (++guard > (1<<18)) { bad=1; break; }
  }
  if (__syncthreads_count(bad)) dead=1;
}
__device__ inline void det_pub(int* go, int ep, int tid){
  if (tid < 64)
    __hip_atomic_store(go + 64*tid, ep, __ATOMIC_RELAXED,
                       __HIP_MEMORY_SCOPE_AGENT);
}

__global__ __launch_bounds__(NTH, 2) void vode_kernel(
  const float* __restrict__ vx,  const float* __restrict__ dts,
  const float* __restrict__ piw, const float* __restrict__ pib,
  const float* __restrict__ w1,  const float* __restrict__ b1,
  const float* __restrict__ w2,  const float* __restrict__ b2,
  const float* __restrict__ wih, const float* __restrict__ whh,
  const float* __restrict__ bih, const float* __restrict__ bhh,
  const float* __restrict__ pow_,const float* __restrict__ pob,
  const float* __restrict__ aw1, const float* __restrict__ ab1,
  const float* __restrict__ aw2,
  float* __restrict__ out, float* __restrict__ ws)
{
  const int g = blockIdx.x, tid = threadIdx.x;
  const int wv = tid>>6, ln = tid&63;
  int*   go     = (int*)ws;
  float* scores = ws + SC_OFFF;
  u64*   ws64   = (u64*)ws;
  u64*   Y64    = ws64 + Y_OFFU;     // [2][256][8]
  u64*   HODE   = ws64 + HODE_OFFU;  // [256][8]
  u64*   HNEW   = ws64 + HNEW_OFFU;  // [256][8]
  int ep = 1, yh = 0, dead = 0;

  // ---------------- detector WG ----------------
  if (g == NWG){
    det_wait(HODE, ep, tid, dead); det_pub(go, ep, tid);
    for (int t=1; t<T; ++t){
      for (int i=0;i<48;++i){
        ++ep;
        det_wait(Y64 + (size_t)(yh&1)*2048, ep, tid, dead);
        det_pub(go, ep, tid);
        ++yh;
      }
      ++ep; det_wait(HODE, ep, tid, dead); det_pub(go, ep, tid);
      ++ep; det_wait(HNEW, ep, tid, dead); det_pub(go, ep, tid);
    }
    return;
  }

  // ---------------- compute WGs ----------------
  __shared__ float part[4][24];
  __shared__ float zb[8], c8[8], b18[8], b28[8];
  __shared__ float myj[6][8], krow[6][8], hrow[8];
  __shared__ float gi_lds[24], gh_lds[24], red8[8];

  // one-time: Mr = (W1·W2)[own 8 rows][thread's 8-col slice]
  float Mr[8][8];
#pragma unroll
  for (int r=0;r<8;++r)
#pragma unroll
    for (int e=0;e<8;++e) Mr[r][e]=0.f;
  for (int m=0;m<HH;++m){
    float w2s[8]; ld8(w2 + (size_t)m*HH + 8*tid, w2s);
#pragma unroll
    for (int r=0;r<8;++r){
      float w1v = w1[(size_t)(8*g+r)*HH + m];
#pragma unroll
      for (int e=0;e<8;++e) Mr[r][e] += w1v*w2s[e];
    }
  }
  // c8 = (W1 b2) own rows
  {
    float b2s[8]; ld8(b2 + 8*tid, b2s);
    float p[8];
#pragma unroll
    for (int r=0;r<8;++r){
      float w1s[8]; ld8(w1 + (size_t)(8*g+r)*HH + 8*tid, w1s);
      p[r]=dot8r(w1s,b2s);
    }
    wave_reduce<8>(p);
    if (ln==0){
#pragma unroll
      for (int r=0;r<8;++r) part[wv][r]=p[r];
    }
    __syncthreads();
    if (tid<8){
      c8[tid]=part[0][tid]+part[1][tid]+part[2][tid]+part[3][tid];
      b18[tid]=b1[8*g+tid]; b28[tid]=b2[8*g+tid];
    }
    __syncthreads();
  }
  float w2r[8][8];
#pragma unroll
  for (int r=0;r<8;++r) ld8(w2 + (size_t)(8*g+r)*HH + 8*tid, w2r[r]);

  float hsl[8];   // full-h slice [8tid..8tid+8)

  auto zb_compute = [&](){
    float p[8];
#pragma unroll
    for (int r=0;r<8;++r){
      float wr[8]; ld8(w1 + (size_t)(8*g+r)*HH + 8*tid, wr);
      p[r]=dot8r(wr,hsl);
    }
    wave_reduce<8>(p);
    if (ln==0){
#pragma unroll
      for (int r=0;r<8;++r) part[wv][r]=p[r];
    }
    __syncthreads();
    if (tid<8) zb[tid]=part[0][tid]+part[1][tid]+part[2][tid]+part[3][tid];
    __syncthreads();
  };

  auto att_proj = [&](int t){
    float p[12];
#pragma unroll
    for (int r=0;r<8;++r){
      float wr[8]; ld8(aw1 + (size_t)(8*g+r)*HH + 8*tid, wr);
      p[r]=dot8r(wr,hsl);
    }
#pragma unroll
    for (int r=0;r<4;++r){
      float wr[8]; ld8(pow_ + (size_t)(4*g+r)*HH + 8*tid, wr);
      p[8+r]=dot8r(wr,hsl);
    }
    wave_reduce<12>(p);
    if (ln==0){
#pragma unroll
      for (int r=0;r<12;++r) part[wv][r]=p[r];
    }
    __syncthreads();
    if (tid<8){
      float u = tanhf(part[0][tid]+part[1][tid]+part[2][tid]+part[3][tid]
                      + ab1[8*g+tid]);
      red8[tid] = u * aw2[8*g+tid];
    } else if (tid<12){
      int d = 4*g + (tid-8);
      out[(size_t)t*D + d] =
        part[0][tid]+part[1][tid]+part[2][tid]+part[3][tid] + pob[d];
    }
    __syncthreads();
    if (tid==0){
      float s = red8[0]+red8[1]+red8[2]+red8[3]+red8[4]+red8[5]+red8[6]+red8[7];
      atomicAdd(&scores[t], s);
    }
    __syncthreads();
  };

  auto gi_compute = [&](int t){
    float xt[4]; ld4(vx + (size_t)t*D + 4*tid, xt);
    float p[24];
#pragma unroll
    for (int rr=0;rr<24;++rr){
      size_t row = (size_t)(rr>>3)*HH + 8*g + (rr&7);
      float wr[4]; ld4(wih + row*D + 4*tid, wr);
      p[rr] = wr[0]*xt[0]+wr[1]*xt[1]+wr[2]*xt[2]+wr[3]*xt[3];
    }
    wave_reduce<24>(p);
    if (ln==0){
#pragma unroll
      for (int rr=0;rr<24;++rr) part[wv][rr]=p[rr];
    }
    __syncthreads();
    if (tid<24){
      size_t row = (size_t)(tid>>3)*HH + 8*g + (tid&7);
      gi_lds[tid] = part[0][tid]+part[1][tid]+part[2][tid]+part[3][tid]
                    + bih[row];
    }
    __syncthreads();
  };

  // ---------- h0 ----------
  {
    float x0[4]; ld4(vx + 4*tid, x0);
    float p[8];
#pragma unroll
    for (int r=0;r<8;++r){
      float wr[4]; ld4(piw + (size_t)(8*g+r)*D + 4*tid, wr);
      p[r] = wr[0]*x0[0]+wr[1]*x0[1]+wr[2]*x0[2]+wr[3]*x0[3];
    }
    wave_reduce<8>(p);
    if (ln==0){
#pragma unroll
      for (int r=0;r<8;++r) part[wv][r]=p[r];
    }
    __syncthreads();
    if (tid<8){
      float v0 = part[0][tid]+part[1][tid]+part[2][tid]+part[3][tid]
                 + pib[8*g+tid];
      hrow[tid] = v0;
      st64(&HODE[g*8+tid], pack(v0, ep));
    }
    consume8(HODE + (size_t)tid*8, ep, hsl, go, dead, tid, g);
    zb_compute();
    if (tid<8 && !dead)
      st64(&Y64[(size_t)(yh&1)*2048 + g*8 + tid],
           pack(tanhf(zb[tid]+b18[tid]), ep+1));
  }

  int pend = 0;
  // ---------- sequential visits ----------
  for (int t=1; t<T; ++t){
    float dt = dts[t] * 0.125f;

    for (int st=0; st<8; ++st){
#pragma unroll
      for (int s=0;s<6;++s){
        ++ep;
        float ysl[8];
        consume8(Y64 + (size_t)(yh&1)*2048 + tid*8, ep, ysl, go, dead, tid, g);
        // critical path: Mr reduce -> next-y store
        float pm[8];
#pragma unroll
        for (int r=0;r<8;++r) pm[r]=dot8r(Mr[r], ysl);
        wave_reduce<8>(pm);
        if (ln==0){
#pragma unroll
          for (int r=0;r<8;++r) part[wv][r]=pm[r];
        }
        __syncthreads();
        if (tid<8){
          myj[s][tid] = part[0][tid]+part[1][tid]+part[2][tid]+part[3][tid];
          if (s<5){
            float z = zb[tid];
            float sm = 0.f;
#pragma unroll
            for (int j=0;j<5;++j)
              if (j <= s) sm += DP_A[s][j]*(myj[j][tid]+c8[tid]);
            z += dt*sm;
            if (!dead)
              st64(&Y64[(size_t)((yh+1)&1)*2048 + g*8 + tid],
                   pack(tanhf(z + b18[tid]), ep+1));
          }
        }
        __syncthreads();
        // off critical path: W2 reduce (krow)
        float pk[8];
#pragma unroll
        for (int r=0;r<8;++r) pk[r]=dot8r(w2r[r], ysl);
        wave_reduce<8>(pk);
        if (ln==0){
#pragma unroll
          for (int r=0;r<8;++r) part[wv][r]=pk[r];
        }
        __syncthreads();
        if (tid<8){
          krow[s][tid] = part[0][tid]+part[1][tid]+part[2][tid]+part[3][tid]
                         + b28[tid];
          if (s==5){
            hrow[tid] += dt*( B0*krow[0][tid] + B2*krow[2][tid]
                            + B3*krow[3][tid] + B4*krow[4][tid]
                            + B5*krow[5][tid] );
            zb[tid]   += dt*( B0*(myj[0][tid]+c8[tid]) + B2*(myj[2][tid]+c8[tid])
                            + B3*(myj[3][tid]+c8[tid]) + B4*(myj[4][tid]+c8[tid])
                            + B5*(myj[5][tid]+c8[tid]) );
            if (!dead){
              if (st<7)
                st64(&Y64[(size_t)((yh+1)&1)*2048 + g*8 + tid],
                     pack(tanhf(zb[tid]+b18[tid]), ep+1));
              else
                st64(&HODE[g*8+tid], pack(hrow[tid], ep+1));
            }
          }
        }
        if (st==0){
          if (s==0) att_proj(pend);          // hidden in hop window
          else if (s==1) gi_compute(t);
        }
        ++yh;
      }
    }

    // ---------- GRU ----------
    ++ep;
    consume8(HODE + (size_t)tid*8, ep, hsl, go, dead, tid, g);  // h_ode
    {
      float p[24];
#pragma unroll
      for (int rr=0;rr<24;++rr){
        size_t row = (size_t)(rr>>3)*HH + 8*g + (rr&7);
        float wr[8]; ld8(whh + row*HH + 8*tid, wr);
        p[rr]=dot8r(wr, hsl);
      }
      wave_reduce<24>(p);
      if (ln==0){
#pragma unroll
        for (int rr=0;rr<24;++rr) part[wv][rr]=p[rr];
      }
      __syncthreads();
      if (tid<24){
        size_t row=(size_t)(tid>>3)*HH + 8*g + (tid&7);
        gh_lds[tid]=part[0][tid]+part[1][tid]+part[2][tid]+part[3][tid]+bhh[row];
      }
      __syncthreads();
      if (tid<8){
        float r_ = 1.f/(1.f+__expf(-(gi_lds[tid]   + gh_lds[tid])));
        float z_ = 1.f/(1.f+__expf(-(gi_lds[8+tid] + gh_lds[8+tid])));
        float n_ = tanhf(gi_lds[16+tid] + r_*gh_lds[16+tid]);
        float hn = (1.f-z_)*n_ + z_*hrow[tid];
        hrow[tid] = hn;
        if (!dead) st64(&HNEW[g*8+tid], pack(hn, ep+1));
      }
      ++ep;
      consume8(HNEW + (size_t)tid*8, ep, hsl, go, dead, tid, g); // h_new
      zb_compute();
      if (t < T-1 && tid<8 && !dead)
        st64(&Y64[(size_t)(yh&1)*2048 + g*8 + tid],
             pack(tanhf(zb[tid]+b18[tid]), ep+1));
      pend = t;
    }
  }

  att_proj(pend);   // t = T-1; ends with __syncthreads (vmcnt drained)

  // final: tagged completion on HODE; WG0 polls all 256 lines, then softmax
  int epf = ep + 1;
  if (tid<8 && !dead) st64(&HODE[g*8+tid], pack(0.f, epf));
  if (g==0){
    if (!dead){
      const u64* line = HODE + (size_t)tid*8;
      int guard=0;
      for (;;){
        int ok=1;
#pragma unroll
        for (int j=0;j<8;++j) ok &= ((int)(ld64(line+j)>>32) >= epf);
        if (ok) break;
        __builtin_amdgcn_s_sleep(2);
        if (++guard > (1<<18)) break;
      }
    }
    __syncthreads();
    if (tid==0){
      float sc[T];
      for (int i=0;i<T;++i) sc[i]=cld(&scores[i]);
      float mx=-1e30f;
      for (int i=0;i<T;++i) if (sc[i]>mx) mx=sc[i];
      float sum=0.f;
      for (int i=0;i<T;++i) sum += __expf(sc[i]-mx);
      for (int i=0;i<T;++i)
        out[(size_t)T*D + i] = __expf(sc[i]-mx)/sum;
    }
  }
}

extern "C" void kernel_launch(void* const* d_in, const int* in_sizes, int n_in,
                              void* d_out, int out_size, void* d_ws, size_t ws_size,
                              hipStream_t stream){
  (void)hipMemsetAsync(d_ws, 0, 90112, stream);  // go + scores + tagged lines
  vode_kernel<<<dim3(NWG+1), dim3(NTH), 0, stream>>>(
      (const float*)d_in[0],  (const float*)d_in[1],  (const float*)d_in[2],
      (const float*)d_in[3],  (const float*)d_in[4],  (const float*)d_in[5],
      (const float*)d_in[6],  (const float*)d_in[7],  (const float*)d_in[8],
      (const float*)d_in[9],  (const float*)d_in[10], (const float*)d_in[11],
      (const float*)d_in[12], (const float*)d_in[13], (const float*)d_in[14],
      (const float*)d_in[15], (const float*)d_in[16],
      (float*)d_out, (float*)d_ws);
}

// Round 20
// 29817.618 us; speedup vs baseline: 1.3169x; 1.3169x over previous
//
#include <hip/hip_runtime.h>

typedef unsigned int u32;
typedef unsigned long long u64;

#define T    128
#define D    1024
#define HH   2048
#define NWG  256
#define NTH  256
#define NREP 8            // tag-line replicas; 32 pollers per line

// ws layout (u64 indices):
//   float scores[128]            @ byte 0 (pad to 4096)
//   u64 Y[2][NREP][2048]         @ u64 512    (256 KB)
//   u64 HODE[NREP][2048]         @ u64 33280  (128 KB)
//   u64 HNEW[NREP][2048]         @ u64 49664  (128 KB)
// memset 528384 B per launch (tags must reset between graph replays)
#define Y_OFFU    512
#define HODE_OFFU 33280
#define HNEW_OFFU 49664

constexpr float DP_A[5][5] = {
  {1.f/5.f, 0.f, 0.f, 0.f, 0.f},
  {3.f/40.f, 9.f/40.f, 0.f, 0.f, 0.f},
  {44.f/45.f, -56.f/15.f, 32.f/9.f, 0.f, 0.f},
  {19372.f/6561.f, -25360.f/2187.f, 64448.f/6561.f, -212.f/729.f, 0.f},
  {9017.f/3168.f, -355.f/33.f, 46732.f/5247.f, 49.f/176.f, -5103.f/18656.f}};
#define B0 (35.f/384.f)
#define B2 (500.f/1113.f)
#define B3 (125.f/192.f)
#define B4 (-2187.f/6784.f)
#define B5 (11.f/84.f)

__device__ inline void ld4(const float* p, float* f){
  float4 q = *reinterpret_cast<const float4*>(p);
  f[0]=q.x; f[1]=q.y; f[2]=q.z; f[3]=q.w;
}
__device__ inline void ld8(const float* p, float* f){
  float4 q0 = *reinterpret_cast<const float4*>(p);
  float4 q1 = *reinterpret_cast<const float4*>(p+4);
  f[0]=q0.x; f[1]=q0.y; f[2]=q0.z; f[3]=q0.w;
  f[4]=q1.x; f[5]=q1.y; f[6]=q1.z; f[7]=q1.w;
}
__device__ inline float dot8r(const float* w, const float* v){
  float s = w[0]*v[0];
  s += w[1]*v[1]; s += w[2]*v[2]; s += w[3]*v[3];
  s += w[4]*v[4]; s += w[5]*v[5]; s += w[6]*v[6]; s += w[7]*v[7];
  return s;
}
__device__ inline float cld(const float* p){
  return __hip_atomic_load(p, __ATOMIC_RELAXED, __HIP_MEMORY_SCOPE_AGENT);
}
__device__ inline void st64(u64* p, u64 v){
  __hip_atomic_store(p, v, __ATOMIC_RELAXED, __HIP_MEMORY_SCOPE_AGENT);
}
__device__ inline u64 ld64(const u64* p){
  return __hip_atomic_load(p, __ATOMIC_RELAXED, __HIP_MEMORY_SCOPE_AGENT);
}
__device__ inline u64 pack(float v, int ep){
  return ((u64)(u32)ep << 32) | (u64)__float_as_uint(v);
}
// producer: replicate own tagged word to all NREP replica blocks
__device__ inline void pub8(u64* base, int idx, u64 v){
#pragma unroll
  for (int r=0;r<NREP;++r) st64(base + r*2048 + idx, v);
}

template<int NR>
__device__ inline void wave_reduce(float* p){
#pragma unroll
  for (int r=0;r<NR;++r){
    float v=p[r];
#pragma unroll
    for (int m=1;m<64;m<<=1) v += __shfl_xor(v, m, 64);
    p[r]=v;
  }
}

// consumer: poll own replica's producer line (32 pollers/line, pure loads)
__device__ inline void consume8(const u64* repbase, int ep, float* out,
                                int& dead, int tid){
  if (dead) return;                      // WG-uniform
  const u64* line = repbase + (size_t)tid*8;
  u64 v[8]; int bad=0, guard=0;
  for (;;){
    int ok=1;
#pragma unroll
    for (int j=0;j<8;++j){ v[j]=ld64(line+j); ok &= ((int)(v[j]>>32) >= ep); }
    if (ok) break;
    __builtin_amdgcn_s_sleep(2);
    if (++guard > (1<<18)) { bad=1; break; }
  }
  if (__syncthreads_count(bad)) dead=1;
#pragma unroll
  for (int j=0;j<8;++j) out[j]=__uint_as_float((u32)v[j]);
}

__global__ __launch_bounds__(NTH) void vode_kernel(
  const float* __restrict__ vx,  const float* __restrict__ dts,
  const float* __restrict__ piw, const float* __restrict__ pib,
  const float* __restrict__ w1,  const float* __restrict__ b1,
  const float* __restrict__ w2,  const float* __restrict__ b2,
  const float* __restrict__ wih, const float* __restrict__ whh,
  const float* __restrict__ bih, const float* __restrict__ bhh,
  const float* __restrict__ pow_,const float* __restrict__ pob,
  const float* __restrict__ aw1, const float* __restrict__ ab1,
  const float* __restrict__ aw2,
  float* __restrict__ out, float* __restrict__ ws)
{
  const int g = blockIdx.x, tid = threadIdx.x;
  const int wv = tid>>6, ln = tid&63;
  const int rep = g>>5;                  // my replica block (32 WGs each)
  float* scores = ws;
  u64*   ws64   = (u64*)ws;
  u64*   Y64    = ws64 + Y_OFFU;     // [2][NREP][2048]
  u64*   HODE   = ws64 + HODE_OFFU;  // [NREP][2048]
  u64*   HNEW   = ws64 + HNEW_OFFU;  // [NREP][2048]
  int ep = 1, yh = 0, dead = 0;

  __shared__ float part[4][24];
  __shared__ float zb[8], c8[8], b18[8], b28[8];
  __shared__ float myj[6][8], krow[6][8], hrow[8];
  __shared__ float gi_lds[24], gh_lds[24], red8[8];

  // one-time: Mr = (W1·W2)[own 8 rows][thread's 8-col slice]
  float Mr[8][8];
#pragma unroll
  for (int r=0;r<8;++r)
#pragma unroll
    for (int e=0;e<8;++e) Mr[r][e]=0.f;
  for (int m=0;m<HH;++m){
    float w2s[8]; ld8(w2 + (size_t)m*HH + 8*tid, w2s);
#pragma unroll
    for (int r=0;r<8;++r){
      float w1v = w1[(size_t)(8*g+r)*HH + m];
#pragma unroll
      for (int e=0;e<8;++e) Mr[r][e] += w1v*w2s[e];
    }
  }
  // c8 = (W1 b2) own rows
  {
    float b2s[8]; ld8(b2 + 8*tid, b2s);
    float p[8];
#pragma unroll
    for (int r=0;r<8;++r){
      float w1s[8]; ld8(w1 + (size_t)(8*g+r)*HH + 8*tid, w1s);
      p[r]=dot8r(w1s,b2s);
    }
    wave_reduce<8>(p);
    if (ln==0){
#pragma unroll
      for (int r=0;r<8;++r) part[wv][r]=p[r];
    }
    __syncthreads();
    if (tid<8){
      c8[tid]=part[0][tid]+part[1][tid]+part[2][tid]+part[3][tid];
      b18[tid]=b1[8*g+tid]; b28[tid]=b2[8*g+tid];
    }
    __syncthreads();
  }
  float w2r[8][8];
#pragma unroll
  for (int r=0;r<8;++r) ld8(w2 + (size_t)(8*g+r)*HH + 8*tid, w2r[r]);

  float hsl[8];   // full-h slice [8tid..8tid+8)

  auto zb_compute = [&](){
    float p[8];
#pragma unroll
    for (int r=0;r<8;++r){
      float wr[8]; ld8(w1 + (size_t)(8*g+r)*HH + 8*tid, wr);
      p[r]=dot8r(wr,hsl);
    }
    wave_reduce<8>(p);
    if (ln==0){
#pragma unroll
      for (int r=0;r<8;++r) part[wv][r]=p[r];
    }
    __syncthreads();
    if (tid<8) zb[tid]=part[0][tid]+part[1][tid]+part[2][tid]+part[3][tid];
    __syncthreads();
  };

  auto att_proj = [&](int t){
    float p[12];
#pragma unroll
    for (int r=0;r<8;++r){
      float wr[8]; ld8(aw1 + (size_t)(8*g+r)*HH + 8*tid, wr);
      p[r]=dot8r(wr,hsl);
    }
#pragma unroll
    for (int r=0;r<4;++r){
      float wr[8]; ld8(pow_ + (size_t)(4*g+r)*HH + 8*tid, wr);
      p[8+r]=dot8r(wr,hsl);
    }
    wave_reduce<12>(p);
    if (ln==0){
#pragma unroll
      for (int r=0;r<12;++r) part[wv][r]=p[r];
    }
    __syncthreads();
    if (tid<8){
      float u = tanhf(part[0][tid]+part[1][tid]+part[2][tid]+part[3][tid]
                      + ab1[8*g+tid]);
      red8[tid] = u * aw2[8*g+tid];
    } else if (tid<12){
      int d = 4*g + (tid-8);
      out[(size_t)t*D + d] =
        part[0][tid]+part[1][tid]+part[2][tid]+part[3][tid] + pob[d];
    }
    __syncthreads();
    if (tid==0){
      float s = red8[0]+red8[1]+red8[2]+red8[3]+red8[4]+red8[5]+red8[6]+red8[7];
      atomicAdd(&scores[t], s);
    }
    __syncthreads();
  };

  auto gi_compute = [&](int t){
    float xt[4]; ld4(vx + (size_t)t*D + 4*tid, xt);
    float p[24];
#pragma unroll
    for (int rr=0;rr<24;++rr){
      size_t row = (size_t)(rr>>3)*HH + 8*g + (rr&7);
      float wr[4]; ld4(wih + row*D + 4*tid, wr);
      p[rr] = wr[0]*xt[0]+wr[1]*xt[1]+wr[2]*xt[2]+wr[3]*xt[3];
    }
    wave_reduce<24>(p);
    if (ln==0){
#pragma unroll
      for (int rr=0;rr<24;++rr) part[wv][rr]=p[rr];
    }
    __syncthreads();
    if (tid<24){
      size_t row = (size_t)(tid>>3)*HH + 8*g + (tid&7);
      gi_lds[tid] = part[0][tid]+part[1][tid]+part[2][tid]+part[3][tid]
                    + bih[row];
    }
    __syncthreads();
  };

  // ---------- h0 ----------
  {
    float x0[4]; ld4(vx + 4*tid, x0);
    float p[8];
#pragma unroll
    for (int r=0;r<8;++r){
      float wr[4]; ld4(piw + (size_t)(8*g+r)*D + 4*tid, wr);
      p[r] = wr[0]*x0[0]+wr[1]*x0[1]+wr[2]*x0[2]+wr[3]*x0[3];
    }
    wave_reduce<8>(p);
    if (ln==0){
#pragma unroll
      for (int r=0;r<8;++r) part[wv][r]=p[r];
    }
    __syncthreads();
    if (tid<8){
      float v0 = part[0][tid]+part[1][tid]+part[2][tid]+part[3][tid]
                 + pib[8*g+tid];
      hrow[tid] = v0;
      pub8(HODE, g*8+tid, pack(v0, ep));
    }
    consume8(HODE + (size_t)rep*2048, ep, hsl, dead, tid);
    zb_compute();
    if (tid<8 && !dead)
      pub8(Y64 + (size_t)(yh&1)*NREP*2048, g*8+tid,
           pack(tanhf(zb[tid]+b18[tid]), ep+1));
  }

  int pend = 0;
  // ---------- sequential visits ----------
  for (int t=1; t<T; ++t){
    float dt = dts[t] * 0.125f;

    for (int st=0; st<8; ++st){
#pragma unroll
      for (int s=0;s<6;++s){
        ++ep;
        float ysl[8];
        consume8(Y64 + (size_t)(yh&1)*NREP*2048 + (size_t)rep*2048,
                 ep, ysl, dead, tid);
        // critical path: Mr reduce -> next-y store
        float pm[8];
#pragma unroll
        for (int r=0;r<8;++r) pm[r]=dot8r(Mr[r], ysl);
        wave_reduce<8>(pm);
        if (ln==0){
#pragma unroll
          for (int r=0;r<8;++r) part[wv][r]=pm[r];
        }
        __syncthreads();
        if (tid<8){
          myj[s][tid] = part[0][tid]+part[1][tid]+part[2][tid]+part[3][tid];
          if (s<5){
            float z = zb[tid];
            float sm = 0.f;
#pragma unroll
            for (int j=0;j<5;++j)
              if (j <= s) sm += DP_A[s][j]*(myj[j][tid]+c8[tid]);
            z += dt*sm;
            if (!dead)
              pub8(Y64 + (size_t)((yh+1)&1)*NREP*2048, g*8+tid,
                   pack(tanhf(z + b18[tid]), ep+1));
          }
        }
        __syncthreads();
        // off critical path: W2 reduce (krow)
        float pk[8];
#pragma unroll
        for (int r=0;r<8;++r) pk[r]=dot8r(w2r[r], ysl);
        wave_reduce<8>(pk);
        if (ln==0){
#pragma unroll
          for (int r=0;r<8;++r) part[wv][r]=pk[r];
        }
        __syncthreads();
        if (tid<8){
          krow[s][tid] = part[0][tid]+part[1][tid]+part[2][tid]+part[3][tid]
                         + b28[tid];
          if (s==5){
            hrow[tid] += dt*( B0*krow[0][tid] + B2*krow[2][tid]
                            + B3*krow[3][tid] + B4*krow[4][tid]
                            + B5*krow[5][tid] );
            zb[tid]   += dt*( B0*(myj[0][tid]+c8[tid]) + B2*(myj[2][tid]+c8[tid])
                            + B3*(myj[3][tid]+c8[tid]) + B4*(myj[4][tid]+c8[tid])
                            + B5*(myj[5][tid]+c8[tid]) );
            if (!dead){
              if (st<7)
                pub8(Y64 + (size_t)((yh+1)&1)*NREP*2048, g*8+tid,
                     pack(tanhf(zb[tid]+b18[tid]), ep+1));
              else
                pub8(HODE, g*8+tid, pack(hrow[tid], ep+1));
            }
          }
        }
        if (st==0){
          if (s==0) att_proj(pend);          // hidden in hop window
          else if (s==1) gi_compute(t);
        }
        ++yh;
      }
    }

    // ---------- GRU ----------
    ++ep;
    consume8(HODE + (size_t)rep*2048, ep, hsl, dead, tid);  // h_ode
    {
      float p[24];
#pragma unroll
      for (int rr=0;rr<24;++rr){
        size_t row = (size_t)(rr>>3)*HH + 8*g + (rr&7);
        float wr[8]; ld8(whh + row*HH + 8*tid, wr);
        p[rr]=dot8r(wr, hsl);
      }
      wave_reduce<24>(p);
      if (ln==0){
#pragma unroll
        for (int rr=0;rr<24;++rr) part[wv][rr]=p[rr];
      }
      __syncthreads();
      if (tid<24){
        size_t row=(size_t)(tid>>3)*HH + 8*g + (tid&7);
        gh_lds[tid]=part[0][tid]+part[1][tid]+part[2][tid]+part[3][tid]+bhh[row];
      }
      __syncthreads();
      if (tid<8){
        float r_ = 1.f/(1.f+__expf(-(gi_lds[tid]   + gh_lds[tid])));
        float z_ = 1.f/(1.f+__expf(-(gi_lds[8+tid] + gh_lds[8+tid])));
        float n_ = tanhf(gi_lds[16+tid] + r_*gh_lds[16+tid]);
        float hn = (1.f-z_)*n_ + z_*hrow[tid];
        hrow[tid] = hn;
        if (!dead) pub8(HNEW, g*8+tid, pack(hn, ep+1));
      }
      ++ep;
      consume8(HNEW + (size_t)rep*2048, ep, hsl, dead, tid);  // h_new
      zb_compute();
      if (t < T-1 && tid<8 && !dead)
        pub8(Y64 + (size_t)(yh&1)*NREP*2048, g*8+tid,
             pack(tanhf(zb[tid]+b18[tid]), ep+1));
      pend = t;
    }
  }

  att_proj(pend);   // t = T-1; ends with __syncthreads (vmcnt drained)

  // final: completion tags on HODE replica 0; WG0 polls, then softmax
  int epf = ep + 1;
  if (tid<8 && !dead) st64(&HODE[g*8+tid], pack(0.f, epf));
  if (g==0){
    if (!dead){
      const u64* line = HODE + (size_t)tid*8;
      int guard=0;
      for (;;){
        int ok=1;
#pragma unroll
        for (int j=0;j<8;++j) ok &= ((int)(ld64(line+j)>>32) >= epf);
        if (ok) break;
        __builtin_amdgcn_s_sleep(2);
        if (++guard > (1<<18)) break;
      }
    }
    __syncthreads();
    if (tid==0){
      float sc[T];
      for (int i=0;i<T;++i) sc[i]=cld(&scores[i]);
      float mx=-1e30f;
      for (int i=0;i<T;++i) if (sc[i]>mx) mx=sc[i];
      float sum=0.f;
      for (int i=0;i<T;++i) sum += __expf(sc[i]-mx);
      for (int i=0;i<T;++i)
        out[(size_t)T*D + i] = __expf(sc[i]-mx)/sum;
    }
  }
}

extern "C" void kernel_launch(void* const* d_in, const int* in_sizes, int n_in,
                              void* d_out, int out_size, void* d_ws, size_t ws_size,
                              hipStream_t stream){
  (void)hipMemsetAsync(d_ws, 0, 528384, stream);  // scores + all tagged lines
  vode_kernel<<<dim3(NWG), dim3(NTH), 0, stream>>>(
      (const float*)d_in[0],  (const float*)d_in[1],  (const float*)d_in[2],
      (const float*)d_in[3],  (const float*)d_in[4],  (const float*)d_in[5],
      (const float*)d_in[6],  (const float*)d_in[7],  (const float*)d_in[8],
      (const float*)d_in[9],  (const float*)d_in[10], (const float*)d_in[11],
      (const float*)d_in[12], (const float*)d_in[13], (const float*)d_in[14],
      (const float*)d_in[15], (const float*)d_in[16],
      (float*)d_out, (float*)d_ws);
}

// Round 21
// 28003.207 us; speedup vs baseline: 1.4022x; 1.0648x over previous
//
#include <hip/hip_runtime.h>

typedef unsigned int u32;

#define T    128
#define D    1024
#define HH   2048
#define NWG  256
#define NTH  256

// ws layout:
//   int  arrival[64 lines]  line i at int 64*i      (bytes 0..16384)
//   int  go[64 lines]       line i at int 4096+64*i (bytes 16384..32768)
//   float scores[128]  @ float 8192                 (bytes 32768..33280)
//   float Y[2][2048]   @ float 9216
//   float HX[2][2048]  @ float 13312
#define GO_OFF    4096
#define WS_SCORES 8192
#define WS_Y      9216
#define WS_HX     13312

constexpr float DP_A[5][5] = {
  {1.f/5.f, 0.f, 0.f, 0.f, 0.f},
  {3.f/40.f, 9.f/40.f, 0.f, 0.f, 0.f},
  {44.f/45.f, -56.f/15.f, 32.f/9.f, 0.f, 0.f},
  {19372.f/6561.f, -25360.f/2187.f, 64448.f/6561.f, -212.f/729.f, 0.f},
  {9017.f/3168.f, -355.f/33.f, 46732.f/5247.f, 49.f/176.f, -5103.f/18656.f}};
#define B0 (35.f/384.f)
#define B2 (500.f/1113.f)
#define B3 (125.f/192.f)
#define B4 (-2187.f/6784.f)
#define B5 (11.f/84.f)

__device__ inline void ld4(const float* p, float* f){
  float4 q = *reinterpret_cast<const float4*>(p);
  f[0]=q.x; f[1]=q.y; f[2]=q.z; f[3]=q.w;
}
__device__ inline void ld8(const float* p, float* f){
  float4 q0 = *reinterpret_cast<const float4*>(p);
  float4 q1 = *reinterpret_cast<const float4*>(p+4);
  f[0]=q0.x; f[1]=q0.y; f[2]=q0.z; f[3]=q0.w;
  f[4]=q1.x; f[5]=q1.y; f[6]=q1.z; f[7]=q1.w;
}
__device__ inline float dot8r(const float* w, const float* v){
  float s = w[0]*v[0];
  s += w[1]*v[1]; s += w[2]*v[2]; s += w[3]*v[3];
  s += w[4]*v[4]; s += w[5]*v[5]; s += w[6]*v[6]; s += w[7]*v[7];
  return s;
}
// agent-scope (coherence-point) data exchange — relaxed: no wb/inv traffic
__device__ inline void cst(float* p, float v){
  __hip_atomic_store(p, v, __ATOMIC_RELAXED, __HIP_MEMORY_SCOPE_AGENT);
}
__device__ inline float cld(const float* p){
  return __hip_atomic_load(p, __ATOMIC_RELAXED, __HIP_MEMORY_SCOPE_AGENT);
}
__device__ inline void cld8(const float* p, float* f){
#pragma unroll
  for (int e=0;e<8;++e) f[e]=cld(p+e);
}

template<int NR>
__device__ inline void wave_reduce(float* p){
#pragma unroll
  for (int r=0;r<NR;++r){
    float v=p[r];
#pragma unroll
    for (int m=1;m<64;m<<=1) v += __shfl_xor(v, m, 64);
    p[r]=v;
  }
}

// ---- grid barrier v7: detector + fan-out. Polled lines are never RMW'd and
// have <=4 pollers each (LLC line-queueing was the 4.6us/hop cost — r8..r16 fit).
// Arrival: 64 lines, 4 WGs RMW each; only detector reads them (1 poller/line).
// Detector (WG0 wave0): lane l polls arrival line l, then stores ep to go line l.
// Wait: tid0 of each WG polls go line (g&63): 1 writer, <=4 pollers.
__device__ inline void garrive(int* bar, int tid, int g){
  __syncthreads();                    // drain vmcnt: prior cst stores complete
  if (tid==0)
    __hip_atomic_fetch_add(bar + 64*(g&63), 1,
                           __ATOMIC_RELAXED, __HIP_MEMORY_SCOPE_AGENT);
}
__device__ inline void gwait(int* bar, int ep, int& dead, int tid, int g){
  int bad=0;
  if (g==0){
    if (tid<64){                      // detector: lockstep poll of 64 lines
      int guard=0;
      while (__hip_atomic_load(bar + 64*tid, __ATOMIC_RELAXED,
                               __HIP_MEMORY_SCOPE_AGENT) < 4*ep){
        __builtin_amdgcn_s_sleep(1);
        if (++guard > (1<<18)) { bad=1; break; }
      }
      // wave reconverges when all lanes' lines are complete -> release
      __hip_atomic_store(bar + GO_OFF + 64*tid, ep,
                         __ATOMIC_RELAXED, __HIP_MEMORY_SCOPE_AGENT);
    }
  } else {
    if (tid==0){
      int guard=0;
      while (__hip_atomic_load(bar + GO_OFF + 64*(g&63), __ATOMIC_RELAXED,
                               __HIP_MEMORY_SCOPE_AGENT) < ep){
        __builtin_amdgcn_s_sleep(1);
        if (++guard > (1<<18)) { bad=1; break; }
      }
    }
  }
  if (__syncthreads_count(bad)) dead=1;
}
__device__ inline void gbar(int* bar, int& ep, int& dead, int tid, int g){
  ++ep;
  if (dead) return;
  garrive(bar, tid, g);
  gwait(bar, ep, dead, tid, g);
}

__global__ __launch_bounds__(NTH, 1) void vode_kernel(
  const float* __restrict__ vx,  const float* __restrict__ dts,
  const float* __restrict__ piw, const float* __restrict__ pib,
  const float* __restrict__ w1,  const float* __restrict__ b1,
  const float* __restrict__ w2,  const float* __restrict__ b2,
  const float* __restrict__ wih, const float* __restrict__ whh,
  const float* __restrict__ bih, const float* __restrict__ bhh,
  const float* __restrict__ pow_,const float* __restrict__ pob,
  const float* __restrict__ aw1, const float* __restrict__ ab1,
  const float* __restrict__ aw2,
  float* __restrict__ out, float* __restrict__ ws)
{
  const int g = blockIdx.x, tid = threadIdx.x;
  const int wv = tid>>6, ln = tid&63;
  int*   bar    = (int*)ws;
  float* scores = ws + WS_SCORES;
  float* ybuf   = ws + WS_Y;      // [2][HH]
  float* hx     = ws + WS_HX;     // [2][HH]
  int ep = 0, dead = 0;

  __shared__ float part[4][24];
  __shared__ float zb[8], c8[8], b18[8], b28[8];
  __shared__ float myj[6][8], krow[6][8], hrow[8];
  __shared__ float gi_lds[24], gh_lds[24], red8[8];

  // ---- one-time: Mr = (W1·W2)[own 8 rows][thread's 8-col slice] ----
  float Mr[8][8];
#pragma unroll
  for (int r=0;r<8;++r)
#pragma unroll
    for (int e=0;e<8;++e) Mr[r][e]=0.f;
  for (int m=0;m<HH;++m){
    float w2s[8]; ld8(w2 + (size_t)m*HH + 8*tid, w2s);
#pragma unroll
    for (int r=0;r<8;++r){
      float w1v = w1[(size_t)(8*g+r)*HH + m];   // wave-uniform scalar load
#pragma unroll
      for (int e=0;e<8;++e) Mr[r][e] += w1v*w2s[e];
    }
  }
  // c8 = (W1 b2) own rows
  {
    float b2s[8]; ld8(b2 + 8*tid, b2s);
    float p[8];
#pragma unroll
    for (int r=0;r<8;++r){
      float w1s[8]; ld8(w1 + (size_t)(8*g+r)*HH + 8*tid, w1s);
      p[r]=dot8r(w1s,b2s);
    }
    wave_reduce<8>(p);
    if (ln==0){
#pragma unroll
      for (int r=0;r<8;++r) part[wv][r]=p[r];
    }
    __syncthreads();
    if (tid<8){
      c8[tid]=part[0][tid]+part[1][tid]+part[2][tid]+part[3][tid];
      b18[tid]=b1[8*g+tid]; b28[tid]=b2[8*g+tid];
    }
    __syncthreads();
  }
  float w2r[8][8];
#pragma unroll
  for (int r=0;r<8;++r) ld8(w2 + (size_t)(8*g+r)*HH + 8*tid, w2r[r]);

  float hsl[8];   // full-h slice [8tid..8tid+8) — Hmat[t] between visits

  auto zb_compute = [&](){
    float p[8];
#pragma unroll
    for (int r=0;r<8;++r){
      float wr[8]; ld8(w1 + (size_t)(8*g+r)*HH + 8*tid, wr);
      p[r]=dot8r(wr,hsl);
    }
    wave_reduce<8>(p);
    if (ln==0){
#pragma unroll
      for (int r=0;r<8;++r) part[wv][r]=p[r];
    }
    __syncthreads();
    if (tid<8) zb[tid]=part[0][tid]+part[1][tid]+part[2][tid]+part[3][tid];
    __syncthreads();
  };

  auto att_proj = [&](int t){
    float p[12];
#pragma unroll
    for (int r=0;r<8;++r){
      float wr[8]; ld8(aw1 + (size_t)(8*g+r)*HH + 8*tid, wr);
      p[r]=dot8r(wr,hsl);
    }
#pragma unroll
    for (int r=0;r<4;++r){
      float wr[8]; ld8(pow_ + (size_t)(4*g+r)*HH + 8*tid, wr);
      p[8+r]=dot8r(wr,hsl);
    }
    wave_reduce<12>(p);
    if (ln==0){
#pragma unroll
      for (int r=0;r<12;++r) part[wv][r]=p[r];
    }
    __syncthreads();
    if (tid<8){
      float u = tanhf(part[0][tid]+part[1][tid]+part[2][tid]+part[3][tid]
                      + ab1[8*g+tid]);
      red8[tid] = u * aw2[8*g+tid];
    } else if (tid<12){
      int d = 4*g + (tid-8);
      out[(size_t)t*D + d] =
        part[0][tid]+part[1][tid]+part[2][tid]+part[3][tid] + pob[d];
    }
    __syncthreads();
    if (tid==0){
      float s = red8[0]+red8[1]+red8[2]+red8[3]+red8[4]+red8[5]+red8[6]+red8[7];
      atomicAdd(&scores[t], s);
    }
    __syncthreads();
  };

  auto gi_compute = [&](int t){
    float xt[4]; ld4(vx + (size_t)t*D + 4*tid, xt);
    float p[24];
#pragma unroll
    for (int rr=0;rr<24;++rr){
      size_t row = (size_t)(rr>>3)*HH + 8*g + (rr&7);
      float wr[4]; ld4(wih + row*D + 4*tid, wr);
      p[rr] = wr[0]*xt[0]+wr[1]*xt[1]+wr[2]*xt[2]+wr[3]*xt[3];
    }
    wave_reduce<24>(p);
    if (ln==0){
#pragma unroll
      for (int rr=0;rr<24;++rr) part[wv][rr]=p[rr];
    }
    __syncthreads();
    if (tid<24){
      size_t row = (size_t)(tid>>3)*HH + 8*g + (tid&7);
      gi_lds[tid] = part[0][tid]+part[1][tid]+part[2][tid]+part[3][tid]
                    + bih[row];
    }
    __syncthreads();
  };

  // ---------- h0 ----------
  {
    float x0[4]; ld4(vx + 4*tid, x0);
    float p[8];
#pragma unroll
    for (int r=0;r<8;++r){
      float wr[4]; ld4(piw + (size_t)(8*g+r)*D + 4*tid, wr);
      p[r] = wr[0]*x0[0]+wr[1]*x0[1]+wr[2]*x0[2]+wr[3]*x0[3];
    }
    wave_reduce<8>(p);
    if (ln==0){
#pragma unroll
      for (int r=0;r<8;++r) part[wv][r]=p[r];
    }
    __syncthreads();
    if (tid<8)
      cst(&hx[8*g+tid],
          part[0][tid]+part[1][tid]+part[2][tid]+part[3][tid] + pib[8*g+tid]);
    gbar(bar, ep, dead, tid, g);
    cld8(hx + 8*tid, hsl);
    if (tid<8) hrow[tid] = cld(&hx[8*g+tid]);
    __syncthreads();
    zb_compute();
  }

  int pp = 0;       // ybuf parity
  int pend = 0;     // att_proj(pend) deferred into hop (st0,s0)
  // ---------- sequential visits ----------
  for (int t=1; t<T; ++t){
    float dt = dts[t] * 0.125f;

    // 8 dopri5 steps, 6 barriers each; att_proj/gi hidden in hop shadows
    for (int st=0; st<8; ++st){
#pragma unroll
      for (int s=0;s<6;++s){
        if (tid<8){
          float z = zb[tid];
          if (s>0){
            float sm = 0.f;
#pragma unroll
            for (int j=0;j<5;++j)
              if (j < s) sm += DP_A[s-1][j]*(myj[j][tid]+c8[tid]);
            z += dt*sm;
          }
          cst(&ybuf[pp*HH + 8*g+tid], tanhf(z + b18[tid]));
        }
        ++ep;
        if (!dead) garrive(bar, tid, g);
        if (st==0){
          if (s==0) att_proj(pend);           // hide in barrier skew window
          else if (s==1) gi_compute(t);       // wih stream off critical path
        }
        if (!dead) gwait(bar, ep, dead, tid, g);
        float ysl[8]; cld8(ybuf + pp*HH + 8*tid, ysl);
        pp ^= 1;
        float p[16];
#pragma unroll
        for (int r=0;r<8;++r){
          p[r]   = dot8r(Mr[r],  ysl);
          p[8+r] = dot8r(w2r[r], ysl);
        }
        wave_reduce<16>(p);
        if (ln==0){
#pragma unroll
          for (int r=0;r<16;++r) part[wv][r]=p[r];
        }
        __syncthreads();
        if (tid<8)
          myj[s][tid] = part[0][tid]+part[1][tid]+part[2][tid]+part[3][tid];
        else if (tid<16)
          krow[s][tid-8] = part[0][tid]+part[1][tid]+part[2][tid]+part[3][tid]
                           + b28[tid-8];
        __syncthreads();
      }
      if (tid<8){
        hrow[tid] += dt*( B0*krow[0][tid] + B2*krow[2][tid] + B3*krow[3][tid]
                        + B4*krow[4][tid] + B5*krow[5][tid] );
        zb[tid]   += dt*( B0*(myj[0][tid]+c8[tid]) + B2*(myj[2][tid]+c8[tid])
                        + B3*(myj[3][tid]+c8[tid]) + B4*(myj[4][tid]+c8[tid])
                        + B5*(myj[5][tid]+c8[tid]) );
      }
      __syncthreads();
    }

    // ---------- GRU ----------
    if (tid<8) cst(&hx[8*g+tid], hrow[tid]);     // hx[0] = h_ode
    gbar(bar, ep, dead, tid, g);
    cld8(hx + 8*tid, hsl);                       // h_ode slice
    {
      float p[24];
#pragma unroll
      for (int rr=0;rr<24;++rr){
        size_t row = (size_t)(rr>>3)*HH + 8*g + (rr&7);
        float wr[8]; ld8(whh + row*HH + 8*tid, wr);
        p[rr]=dot8r(wr, hsl);
      }
      wave_reduce<24>(p);
      if (ln==0){
#pragma unroll
        for (int rr=0;rr<24;++rr) part[wv][rr]=p[rr];
      }
      __syncthreads();
      if (tid<24){
        size_t row=(size_t)(tid>>3)*HH + 8*g + (tid&7);
        gh_lds[tid]=part[0][tid]+part[1][tid]+part[2][tid]+part[3][tid]+bhh[row];
      }
      __syncthreads();
      if (tid<8){
        float r_ = 1.f/(1.f+__expf(-(gi_lds[tid]   + gh_lds[tid])));
        float z_ = 1.f/(1.f+__expf(-(gi_lds[8+tid] + gh_lds[8+tid])));
        float n_ = tanhf(gi_lds[16+tid] + r_*gh_lds[16+tid]);
        float hn = (1.f-z_)*n_ + z_*hrow[tid];
        hrow[tid] = hn;
        cst(&hx[HH + 8*g+tid], hn);              // hx[1] = h_new
      }
      gbar(bar, ep, dead, tid, g);
      cld8(hx + HH + 8*tid, hsl);                // h_new = Hmat[t] slice
      zb_compute();
      pend = t;                                  // att_proj(t) deferred
    }
  }

  att_proj(T-1);                                 // last pending row
  gbar(bar, ep, dead, tid, g);                   // all scores visible

  // softmax over scores -> alpha
  if (g==0 && tid==0){
    float sc[T];
    for (int i=0;i<T;++i) sc[i]=cld(&scores[i]);
    float mx=-1e30f;
    for (int i=0;i<T;++i) if (sc[i]>mx) mx=sc[i];
    float sum=0.f;
    for (int i=0;i<T;++i) sum += __expf(sc[i]-mx);
    for (int i=0;i<T;++i)
      out[(size_t)T*D + i] = __expf(sc[i]-mx)/sum;
  }
}

extern "C" void kernel_launch(void* const* d_in, const int* in_sizes, int n_in,
                              void* d_out, int out_size, void* d_ws, size_t ws_size,
                              hipStream_t stream){
  (void)hipMemsetAsync(d_ws, 0, 36864, stream);   // arrival + go lines + scores
  vode_kernel<<<dim3(NWG), dim3(NTH), 0, stream>>>(
      (const float*)d_in[0],  (const float*)d_in[1],  (const float*)d_in[2],
      (const float*)d_in[3],  (const float*)d_in[4],  (const float*)d_in[5],
      (const float*)d_in[6],  (const float*)d_in[7],  (const float*)d_in[8],
      (const float*)d_in[9],  (const float*)d_in[10], (const float*)d_in[11],
      (const float*)d_in[12], (const float*)d_in[13], (const float*)d_in[14],
      (const float*)d_in[15], (const float*)d_in[16],
      (float*)d_out, (float*)d_ws);
}